// Round 5
// baseline (549.236 us; speedup 1.0000x reference)
//
#include <hip/hip_runtime.h>
#include <hip/hip_bf16.h>

typedef __attribute__((ext_vector_type(4))) int   int32x4;
typedef __attribute__((ext_vector_type(4))) float float4v;

// ---------------- stats layout (floats at ws+0) ----------------
// [0]=absmax_x [1]=absmax_w1 [2]=absmax_w2 [3]=absmax_w3 [4]=hmax1 [5]=hmax2

__global__ void init_stats(float* stats) {
    if (threadIdx.x < 64) stats[threadIdx.x] = 0.0f;
}

__global__ void zero_kernel(int32x4* __restrict__ p, long n4) {
    long i = (long)blockIdx.x * blockDim.x + threadIdx.x;
    long stride = (long)gridDim.x * blockDim.x;
    int32x4 z = {0, 0, 0, 0};
    for (; i < n4; i += stride) p[i] = z;
}

// ---------------- max|x| reduction ----------------
// Chunked: each block-iteration owns a contiguous 4096-float chunk (1024 float4).
// 4 fully-coalesced float4 loads/thread, block reduce, ONE atomic per block.
__global__ void maxabs_kernel(const float* __restrict__ src, long nchunk, float* __restrict__ out) {
    const int tid  = threadIdx.x;
    const int lane = tid & 63;
    const int wid  = tid >> 6;
    __shared__ float red[4];
    float m0 = 0.0f, m1 = 0.0f, m2 = 0.0f, m3 = 0.0f;
    for (long c = blockIdx.x; c < nchunk; c += gridDim.x) {
        const float4v* p = (const float4v*)src + c * 1024 + tid;
        float4v v0 = p[0], v1 = p[256], v2 = p[512], v3 = p[768];
        m0 = fmaxf(m0, fmaxf(fmaxf(fabsf(v0.x), fabsf(v0.y)), fmaxf(fabsf(v0.z), fabsf(v0.w))));
        m1 = fmaxf(m1, fmaxf(fmaxf(fabsf(v1.x), fabsf(v1.y)), fmaxf(fabsf(v1.z), fabsf(v1.w))));
        m2 = fmaxf(m2, fmaxf(fmaxf(fabsf(v2.x), fabsf(v2.y)), fmaxf(fabsf(v2.z), fabsf(v2.w))));
        m3 = fmaxf(m3, fmaxf(fmaxf(fabsf(v3.x), fabsf(v3.y)), fmaxf(fabsf(v3.z), fabsf(v3.w))));
    }
    float m = fmaxf(fmaxf(m0, m1), fmaxf(m2, m3));
    #pragma unroll
    for (int off = 32; off; off >>= 1) m = fmaxf(m, __shfl_xor(m, off, 64));
    if (lane == 0) red[wid] = m;
    __syncthreads();
    if (tid == 0) {
        float r = fmaxf(fmaxf(red[0], red[1]), fmaxf(red[2], red[3]));
        atomicMax((unsigned int*)out, __float_as_uint(r));
    }
}

// ---------------- fp32 -> int8 quantize: clip(rint(x/scale), lo, hi) ----------------
__global__ void quant_kernel(const float* __restrict__ src, signed char* __restrict__ dst,
                             const float* __restrict__ stats, int slot,
                             float lo, float hi, long nchunk) {
    const float scale = stats[slot] / 127.0f;
    const int tid = threadIdx.x;
    for (long c = blockIdx.x; c < nchunk; c += gridDim.x) {
        const float4v* p = (const float4v*)src + c * 1024 + tid;
        int* d = (int*)dst + c * 1024 + tid;
        float4v v0 = p[0], v1 = p[256], v2 = p[512], v3 = p[768];
        float4v vs[4] = {v0, v1, v2, v3};
        int packed[4];
        #pragma unroll
        for (int j = 0; j < 4; ++j) {
            float4v v = vs[j];
            int b0 = (int)fminf(fmaxf(rintf(v.x / scale), lo), hi);
            int b1 = (int)fminf(fmaxf(rintf(v.y / scale), lo), hi);
            int b2 = (int)fminf(fmaxf(rintf(v.z / scale), lo), hi);
            int b3 = (int)fminf(fmaxf(rintf(v.w / scale), lo), hi);
            packed[j] = (b0 & 0xff) | ((b1 & 0xff) << 8) | ((b2 & 0xff) << 16) | ((b3 & 0xff) << 24);
        }
        d[0]   = packed[0];
        d[256] = packed[1];
        d[512] = packed[2];
        d[768] = packed[3];
    }
}

// ---------------- split-K int8 GEMM: Acc[M,ldacc] += A[M,K(slice)] @ Bw[N,K(slice)]^T ----------------
// Pure int32 partial accumulation via atomicAdd (exact, commutative).
// 3-stage LDS pipeline, counted vmcnt, XOR-swizzled LDS (pre-swizzled global source).
// grid = (N/BN, M/BM, SPLITK); each z-block covers kslice = K/SPLITK.
template <int BM, int BN, int FR, int FC>
__global__ __launch_bounds__(256, 4)
void gemm_q8(const signed char* __restrict__ A, const signed char* __restrict__ Bw,
             int* __restrict__ Acc, int K, int kslice, int ldacc) {
    constexpr int BK = 64;
    constexpr int NWC = BN / (FC * 16);
    constexpr int L = BM / 64 + BN / 64;         // gload_lds per thread per stage
    static_assert((BM / (FR * 16)) * (BN / (FC * 16)) == 4, "4 waves");
    constexpr int LDS_A = BM * BK;
    constexpr int LDS_TILE = (BM + BN) * BK;
    __shared__ __align__(16) signed char lds[3][LDS_TILE];

    const int tid  = threadIdx.x;
    const int wid  = tid >> 6;
    const int lane = tid & 63;
    const int wr   = wid / NWC;
    const int wc   = wid % NWC;

    const int brow  = blockIdx.y * BM;
    const int bcol  = blockIdx.x * BN;
    const int kbase = blockIdx.z * kslice;

    const signed char* Ab = A  + (long)brow * K + kbase;
    const signed char* Bb = Bw + (long)bcol * K + kbase;

    const int srow = tid >> 2;                        // row within tile handled when staging
    const int scb  = (tid & 3) * 16;                  // LDS byte column (16B chunk), linear dest
    const int scsrc = scb ^ (((srow >> 1) & 3) << 4); // inverse-swizzled global column

    int32x4 zero = {0, 0, 0, 0};
    int32x4 acc[FR][FC];
    #pragma unroll
    for (int r = 0; r < FR; ++r)
        #pragma unroll
        for (int c = 0; c < FC; ++c) acc[r][c] = zero;

    auto stage = [&](int buf, int kt) {
        #pragma unroll
        for (int i = 0; i < BM / 64; ++i) {
            __builtin_amdgcn_global_load_lds(
                (const __attribute__((address_space(1))) void*)(Ab + (long)(srow + i * 64) * K + kt + scsrc),
                (__attribute__((address_space(3))) void*)(&lds[buf][(srow + i * 64) * BK + scb]),
                16, 0, 0);
        }
        #pragma unroll
        for (int i = 0; i < BN / 64; ++i) {
            __builtin_amdgcn_global_load_lds(
                (const __attribute__((address_space(1))) void*)(Bb + (long)(srow + i * 64) * K + kt + scsrc),
                (__attribute__((address_space(3))) void*)(&lds[buf][LDS_A + (srow + i * 64) * BK + scb]),
                16, 0, 0);
        }
    };

    const int nt = kslice / BK;
    stage(0, 0);
    if (nt > 1) stage(1, BK);

    for (int t = 0; t < nt; ++t) {
        if (t + 1 < nt) {
            asm volatile("s_waitcnt vmcnt(%0)\n\ts_barrier" :: "n"(L) : "memory");
        } else {
            asm volatile("s_waitcnt vmcnt(0)\n\ts_barrier" ::: "memory");
        }
        if (t + 2 < nt) stage((t + 2) % 3, (t + 2) * BK);

        const signed char* la = &lds[t % 3][0];
        const signed char* lb = &lds[t % 3][LDS_A];
        int32x4 af[FR], bf[FC];
        #pragma unroll
        for (int r = 0; r < FR; ++r) {
            const int row = wr * (FR * 16) + r * 16 + (lane & 15);
            const int col = ((lane >> 4) * 16) ^ (((row >> 1) & 3) << 4);
            af[r] = *(const int32x4*)(la + row * BK + col);
        }
        #pragma unroll
        for (int c = 0; c < FC; ++c) {
            const int row = wc * (FC * 16) + c * 16 + (lane & 15);
            const int col = ((lane >> 4) * 16) ^ (((row >> 1) & 3) << 4);
            bf[c] = *(const int32x4*)(lb + row * BK + col);
        }

        #pragma unroll
        for (int r = 0; r < FR; ++r)
            #pragma unroll
            for (int c = 0; c < FC; ++c)
                acc[r][c] = __builtin_amdgcn_mfma_i32_16x16x64_i8(af[r], bf[c], acc[r][c], 0, 0, 0);
    }

    // epilogue: exact int32 partial-sum into Acc
    #pragma unroll
    for (int c = 0; c < FC; ++c) {
        const int col = bcol + wc * (FC * 16) + c * 16 + (lane & 15);
        #pragma unroll
        for (int r = 0; r < FR; ++r) {
            const int row0 = brow + wr * (FR * 16) + r * 16 + (lane >> 4) * 4;
            #pragma unroll
            for (int j = 0; j < 4; ++j)
                atomicAdd(&Acc[(long)(row0 + j) * ldacc + col], acc[r][c][j]);
        }
    }
}

// ---------------- finish (fc1/fc2): in-place int32 acc -> fp32, bias+relu+max ----------------
// buf[i] (int32) -> out value (fp32) at same index; colmask = N-1 (N power of 2).
__global__ void finish_relu_kernel(int* __restrict__ buf, const float* __restrict__ bias,
                                   float* __restrict__ stats, int a_slot, int w_slot, int h_slot,
                                   long n4, int colmask) {
    const float s = (stats[a_slot] / 127.0f) * (stats[w_slot] / 127.0f);
    const int tid = threadIdx.x;
    const int lane = tid & 63;
    const int wid = tid >> 6;
    __shared__ float red[4];
    float lmax = 0.0f;
    long i = (long)blockIdx.x * blockDim.x + tid;
    long stride = (long)gridDim.x * blockDim.x;
    for (; i < n4; i += stride) {
        int32x4 a = ((int32x4*)buf)[i];
        float4v v;
        #pragma unroll
        for (int j = 0; j < 4; ++j) {
            int col = (int)((i * 4 + j) & colmask);
            float bint = rintf(bias[col] / s);
            float val = ((float)a[j] + bint) * s;
            val = fmaxf(val, 0.0f);
            v[j] = val;
            lmax = fmaxf(lmax, val);
        }
        ((float4v*)buf)[i] = v;
    }
    #pragma unroll
    for (int off = 32; off; off >>= 1) lmax = fmaxf(lmax, __shfl_xor(lmax, off, 64));
    if (lane == 0) red[wid] = lmax;
    __syncthreads();
    if (tid == 0) {
        float r = fmaxf(fmaxf(red[0], red[1]), fmaxf(red[2], red[3]));
        atomicMax((unsigned int*)&stats[h_slot], __float_as_uint(r));
    }
}

// ---------------- finish (fc3): acc[512][1024] -> out[512][1000], bias, no relu ----------------
__global__ void finish3_kernel(const int* __restrict__ acc, const float* __restrict__ bias,
                               const float* __restrict__ stats, int a_slot, int w_slot,
                               float* __restrict__ out, int ncols) {
    const float s = (stats[a_slot] / 127.0f) * (stats[w_slot] / 127.0f);
    const int row = blockIdx.x;
    for (int col = threadIdx.x; col < ncols; col += blockDim.x) {
        float bint = rintf(bias[col] / s);
        out[(long)row * ncols + col] = ((float)acc[(long)row * 1024 + col] + bint) * s;
    }
}

static inline long lminl(long a, long b) { return a < b ? a : b; }

extern "C" void kernel_launch(void* const* d_in, const int* in_sizes, int n_in,
                              void* d_out, int out_size, void* d_ws, size_t ws_size,
                              hipStream_t stream) {
    const float* x  = (const float*)d_in[0];
    const float* w1 = (const float*)d_in[1];
    const float* b1 = (const float*)d_in[2];
    const float* w2 = (const float*)d_in[3];
    const float* b2 = (const float*)d_in[4];
    const float* w3 = (const float*)d_in[5];
    const float* b3 = (const float*)d_in[6];
    float* out = (float*)d_out;

    constexpr int B = 512, DIN = 9216, DH = 4096, DOUT = 1000;

    // workspace carve-up
    char* ws = (char*)d_ws;
    float*       stats = (float*)ws;                       // 256 B
    signed char* xq    = (signed char*)(ws + 256);         // 512*9216
    signed char* w1q   = xq  + (size_t)B * DIN;            // 4096*9216
    signed char* w2q   = w1q + (size_t)DH * DIN;           // 4096*4096
    signed char* w3q   = w2q + (size_t)DH * DH;            // 1024*4096 (padded rows)
    signed char* h1q   = w3q + (size_t)1024 * DH;          // 512*4096
    signed char* h2q   = h1q + (size_t)B * DH;             // 512*4096
    float*       hbuf  = (float*)(h2q + (size_t)B * DH);   // 512*4096 fp32; doubles as int32 acc
    const size_t need  = 256 + (size_t)B*DIN + (size_t)DH*DIN + (size_t)DH*DH + (size_t)1024*DH
                       + 2*(size_t)B*DH + (size_t)B*DH*4;
    if (ws_size < need) return;  // avoid corrupting memory if workspace too small

    init_stats<<<1, 64, 0, stream>>>(stats);

    auto launch_maxabs = [&](const float* p, long n, int slot) {
        long nchunk = n / 4096;                 // all sizes are multiples of 4096 floats
        int blocks = (int)lminl(nchunk, 2048);
        maxabs_kernel<<<blocks, 256, 0, stream>>>(p, nchunk, stats + slot);
    };
    auto launch_quant = [&](const float* p, signed char* q, long n, int slot, float lo) {
        long nchunk = n / 4096;
        int blocks = (int)lminl(nchunk, 2048);
        quant_kernel<<<blocks, 256, 0, stream>>>(p, q, stats, slot, lo, 127.0f, nchunk);
    };

    // quantize inputs (maxabs then quant back-to-back for L3 reuse)
    launch_maxabs(x, (long)B * DIN, 0);
    launch_quant(x, xq, (long)B * DIN, 0, -128.0f);      // activations: lo = -N_LEVELS-1
    launch_maxabs(w1, (long)DH * DIN, 1);
    launch_quant(w1, w1q, (long)DH * DIN, 1, -127.0f);   // weights: lo = -N_LEVELS
    launch_maxabs(w2, (long)DH * DH, 2);
    launch_quant(w2, w2q, (long)DH * DH, 2, -127.0f);
    launch_maxabs(w3, (long)DOUT * DH, 3);
    launch_quant(w3, w3q, (long)DOUT * DH, 3, -127.0f);

    int* acc = (int*)hbuf;
    const long n4_h = (long)B * DH / 4;   // 524288

    // fc1: zero acc, split-K GEMM (K=9216, 4 slices of 2304), finish in-place, quant h1
    zero_kernel<<<2048, 256, 0, stream>>>((int32x4*)acc, n4_h);
    gemm_q8<64, 128, 2, 4><<<dim3(DH / 128, B / 64, 4), 256, 0, stream>>>(
        xq, w1q, acc, DIN, DIN / 4, DH);
    finish_relu_kernel<<<2048, 256, 0, stream>>>(acc, b1, stats, 0, 1, 4, n4_h, DH - 1);
    launch_quant(hbuf, h1q, (long)B * DH, 4, -128.0f);

    // fc2: same, K=4096 in 4 slices of 1024
    zero_kernel<<<2048, 256, 0, stream>>>((int32x4*)acc, n4_h);
    gemm_q8<64, 128, 2, 4><<<dim3(DH / 128, B / 64, 4), 256, 0, stream>>>(
        h1q, w2q, acc, DH, DH / 4, DH);
    finish_relu_kernel<<<2048, 256, 0, stream>>>(acc, b2, stats, 4, 2, 5, n4_h, DH - 1);
    launch_quant(hbuf, h2q, (long)B * DH, 5, -128.0f);

    // fc3: acc reuses hbuf (dead after h2 quant); 512x1024 int32, cols>=1000 are garbage (never read)
    zero_kernel<<<512, 256, 0, stream>>>((int32x4*)acc, (long)B * 1024 / 4);
    gemm_q8<64, 64, 2, 2><<<dim3(16, B / 64, 4), 256, 0, stream>>>(
        h2q, w3q, acc, DH, DH / 4, 1024);
    finish3_kernel<<<B, 256, 0, stream>>>(acc, b3, stats, 5, 3, out, DOUT);
}

// Round 6
// 523.764 us; speedup vs baseline: 1.0486x; 1.0486x over previous
//
#include <hip/hip_runtime.h>
#include <hip/hip_bf16.h>

typedef __attribute__((ext_vector_type(4))) int   int32x4;
typedef __attribute__((ext_vector_type(4))) float float4v;

// ---------------- stats layout (floats at ws+0) ----------------
// [0]=absmax_x [1]=absmax_w1 [2]=absmax_w2 [3]=absmax_w3 [4]=hmax1 [5]=hmax2

__global__ void init_stats(float* stats) {
    if (threadIdx.x < 64) stats[threadIdx.x] = 0.0f;
}

// ---------------- max|x| reduction ----------------
// Chunked: each block-iteration owns a contiguous 4096-float chunk (1024 float4).
// 4 fully-coalesced float4 loads/thread, block reduce, ONE atomic per block.
__global__ void maxabs_kernel(const float* __restrict__ src, long nchunk, float* __restrict__ out) {
    const int tid  = threadIdx.x;
    const int lane = tid & 63;
    const int wid  = tid >> 6;
    __shared__ float red[4];
    float m0 = 0.0f, m1 = 0.0f, m2 = 0.0f, m3 = 0.0f;
    for (long c = blockIdx.x; c < nchunk; c += gridDim.x) {
        const float4v* p = (const float4v*)src + c * 1024 + tid;
        float4v v0 = p[0], v1 = p[256], v2 = p[512], v3 = p[768];
        m0 = fmaxf(m0, fmaxf(fmaxf(fabsf(v0.x), fabsf(v0.y)), fmaxf(fabsf(v0.z), fabsf(v0.w))));
        m1 = fmaxf(m1, fmaxf(fmaxf(fabsf(v1.x), fabsf(v1.y)), fmaxf(fabsf(v1.z), fabsf(v1.w))));
        m2 = fmaxf(m2, fmaxf(fmaxf(fabsf(v2.x), fabsf(v2.y)), fmaxf(fabsf(v2.z), fabsf(v2.w))));
        m3 = fmaxf(m3, fmaxf(fmaxf(fabsf(v3.x), fabsf(v3.y)), fmaxf(fabsf(v3.z), fabsf(v3.w))));
    }
    float m = fmaxf(fmaxf(m0, m1), fmaxf(m2, m3));
    #pragma unroll
    for (int off = 32; off; off >>= 1) m = fmaxf(m, __shfl_xor(m, off, 64));
    if (lane == 0) red[wid] = m;
    __syncthreads();
    if (tid == 0) {
        float r = fmaxf(fmaxf(red[0], red[1]), fmaxf(red[2], red[3]));
        atomicMax((unsigned int*)out, __float_as_uint(r));
    }
}

// ---------------- fp32 -> int8 quantize: clip(rint(x/scale), lo, hi) ----------------
__global__ void quant_kernel(const float* __restrict__ src, signed char* __restrict__ dst,
                             const float* __restrict__ stats, int slot,
                             float lo, float hi, long nchunk) {
    const float scale = stats[slot] / 127.0f;
    const int tid = threadIdx.x;
    for (long c = blockIdx.x; c < nchunk; c += gridDim.x) {
        const float4v* p = (const float4v*)src + c * 1024 + tid;
        int* d = (int*)dst + c * 1024 + tid;
        float4v v0 = p[0], v1 = p[256], v2 = p[512], v3 = p[768];
        float4v vs[4] = {v0, v1, v2, v3};
        int packed[4];
        #pragma unroll
        for (int j = 0; j < 4; ++j) {
            float4v v = vs[j];
            int b0 = (int)fminf(fmaxf(rintf(v.x / scale), lo), hi);
            int b1 = (int)fminf(fmaxf(rintf(v.y / scale), lo), hi);
            int b2 = (int)fminf(fmaxf(rintf(v.z / scale), lo), hi);
            int b3 = (int)fminf(fmaxf(rintf(v.w / scale), lo), hi);
            packed[j] = (b0 & 0xff) | ((b1 & 0xff) << 8) | ((b2 & 0xff) << 16) | ((b3 & 0xff) << 24);
        }
        d[0]   = packed[0];
        d[256] = packed[1];
        d[512] = packed[2];
        d[768] = packed[3];
    }
}

// ---------------- split-K int8 GEMM: Acc[z][M,ldacc] = A[M,Kslice_z] @ Bw[N,Kslice_z]^T ----------------
// Each z-slice writes its PRIVATE acc buffer with plain stores (no atomics, no pre-zero).
// 3-stage LDS pipeline, counted vmcnt, XOR-swizzled LDS (pre-swizzled global source).
// grid = (N/BN, M/BM, SPLITK); each z-block covers kslice = K/SPLITK.
template <int BM, int BN, int FR, int FC>
__global__ __launch_bounds__(256, 4)
void gemm_q8(const signed char* __restrict__ A, const signed char* __restrict__ Bw,
             int* __restrict__ Acc, int K, int kslice, int ldacc, long accstride) {
    constexpr int BK = 64;
    constexpr int NWC = BN / (FC * 16);
    constexpr int L = BM / 64 + BN / 64;         // gload_lds per thread per stage
    static_assert((BM / (FR * 16)) * (BN / (FC * 16)) == 4, "4 waves");
    constexpr int LDS_A = BM * BK;
    constexpr int LDS_TILE = (BM + BN) * BK;
    __shared__ __align__(16) signed char lds[3][LDS_TILE];

    const int tid  = threadIdx.x;
    const int wid  = tid >> 6;
    const int lane = tid & 63;
    const int wr   = wid / NWC;
    const int wc   = wid % NWC;

    const int brow  = blockIdx.y * BM;
    const int bcol  = blockIdx.x * BN;
    const int kbase = blockIdx.z * kslice;
    int* __restrict__ Accz = Acc + (long)blockIdx.z * accstride;

    const signed char* Ab = A  + (long)brow * K + kbase;
    const signed char* Bb = Bw + (long)bcol * K + kbase;

    const int srow = tid >> 2;                        // row within tile handled when staging
    const int scb  = (tid & 3) * 16;                  // LDS byte column (16B chunk), linear dest
    const int scsrc = scb ^ (((srow >> 1) & 3) << 4); // inverse-swizzled global column

    int32x4 zero = {0, 0, 0, 0};
    int32x4 acc[FR][FC];
    #pragma unroll
    for (int r = 0; r < FR; ++r)
        #pragma unroll
        for (int c = 0; c < FC; ++c) acc[r][c] = zero;

    auto stage = [&](int buf, int kt) {
        #pragma unroll
        for (int i = 0; i < BM / 64; ++i) {
            __builtin_amdgcn_global_load_lds(
                (const __attribute__((address_space(1))) void*)(Ab + (long)(srow + i * 64) * K + kt + scsrc),
                (__attribute__((address_space(3))) void*)(&lds[buf][(srow + i * 64) * BK + scb]),
                16, 0, 0);
        }
        #pragma unroll
        for (int i = 0; i < BN / 64; ++i) {
            __builtin_amdgcn_global_load_lds(
                (const __attribute__((address_space(1))) void*)(Bb + (long)(srow + i * 64) * K + kt + scsrc),
                (__attribute__((address_space(3))) void*)(&lds[buf][LDS_A + (srow + i * 64) * BK + scb]),
                16, 0, 0);
        }
    };

    const int nt = kslice / BK;
    stage(0, 0);
    if (nt > 1) stage(1, BK);

    for (int t = 0; t < nt; ++t) {
        if (t + 1 < nt) {
            asm volatile("s_waitcnt vmcnt(%0)\n\ts_barrier" :: "n"(L) : "memory");
        } else {
            asm volatile("s_waitcnt vmcnt(0)\n\ts_barrier" ::: "memory");
        }
        if (t + 2 < nt) stage((t + 2) % 3, (t + 2) * BK);

        const signed char* la = &lds[t % 3][0];
        const signed char* lb = &lds[t % 3][LDS_A];
        int32x4 af[FR], bf[FC];
        #pragma unroll
        for (int r = 0; r < FR; ++r) {
            const int row = wr * (FR * 16) + r * 16 + (lane & 15);
            const int col = ((lane >> 4) * 16) ^ (((row >> 1) & 3) << 4);
            af[r] = *(const int32x4*)(la + row * BK + col);
        }
        #pragma unroll
        for (int c = 0; c < FC; ++c) {
            const int row = wc * (FC * 16) + c * 16 + (lane & 15);
            const int col = ((lane >> 4) * 16) ^ (((row >> 1) & 3) << 4);
            bf[c] = *(const int32x4*)(lb + row * BK + col);
        }

        #pragma unroll
        for (int r = 0; r < FR; ++r)
            #pragma unroll
            for (int c = 0; c < FC; ++c)
                acc[r][c] = __builtin_amdgcn_mfma_i32_16x16x64_i8(af[r], bf[c], acc[r][c], 0, 0, 0);
    }

    // epilogue: plain stores into this slice's private acc (every element written once)
    #pragma unroll
    for (int c = 0; c < FC; ++c) {
        const int col = bcol + wc * (FC * 16) + c * 16 + (lane & 15);
        #pragma unroll
        for (int r = 0; r < FR; ++r) {
            const int row0 = brow + wr * (FR * 16) + r * 16 + (lane >> 4) * 4;
            #pragma unroll
            for (int j = 0; j < 4; ++j)
                Accz[(long)(row0 + j) * ldacc + col] = acc[r][c][j];
        }
    }
}

// ---------------- finish (fc1/fc2): sum 4 int32 slices -> fp32, bias+relu+max ----------------
__global__ void finish_relu_kernel(const int* __restrict__ acc, long accstride,
                                   const float* __restrict__ bias,
                                   float* __restrict__ stats, int a_slot, int w_slot, int h_slot,
                                   float* __restrict__ outbuf, long n4, int colmask) {
    const float s = (stats[a_slot] / 127.0f) * (stats[w_slot] / 127.0f);
    const int tid = threadIdx.x;
    const int lane = tid & 63;
    const int wid = tid >> 6;
    __shared__ float red[4];
    float lmax = 0.0f;
    long i = (long)blockIdx.x * blockDim.x + tid;
    long stride = (long)gridDim.x * blockDim.x;
    for (; i < n4; i += stride) {
        int32x4 a0 = ((const int32x4*)acc)[i];
        int32x4 a1 = ((const int32x4*)(acc + accstride))[i];
        int32x4 a2 = ((const int32x4*)(acc + 2 * accstride))[i];
        int32x4 a3 = ((const int32x4*)(acc + 3 * accstride))[i];
        float4v v;
        #pragma unroll
        for (int j = 0; j < 4; ++j) {
            int sum = a0[j] + a1[j] + a2[j] + a3[j];
            int col = (int)((i * 4 + j) & colmask);
            float bint = rintf(bias[col] / s);
            float val = ((float)sum + bint) * s;
            val = fmaxf(val, 0.0f);
            v[j] = val;
            lmax = fmaxf(lmax, val);
        }
        ((float4v*)outbuf)[i] = v;
    }
    #pragma unroll
    for (int off = 32; off; off >>= 1) lmax = fmaxf(lmax, __shfl_xor(lmax, off, 64));
    if (lane == 0) red[wid] = lmax;
    __syncthreads();
    if (tid == 0) {
        float r = fmaxf(fmaxf(red[0], red[1]), fmaxf(red[2], red[3]));
        atomicMax((unsigned int*)&stats[h_slot], __float_as_uint(r));
    }
}

// ---------------- finish (fc3): sum 4 slices of acc[512][1024] -> out[512][1000], bias ----------------
__global__ void finish3_kernel(const int* __restrict__ acc, long accstride,
                               const float* __restrict__ bias,
                               const float* __restrict__ stats, int a_slot, int w_slot,
                               float* __restrict__ out, int ncols) {
    const float s = (stats[a_slot] / 127.0f) * (stats[w_slot] / 127.0f);
    const int row = blockIdx.x;
    for (int col = threadIdx.x; col < ncols; col += blockDim.x) {
        long idx = (long)row * 1024 + col;
        int sum = acc[idx] + acc[idx + accstride] + acc[idx + 2 * accstride] + acc[idx + 3 * accstride];
        float bint = rintf(bias[col] / s);
        out[(long)row * ncols + col] = ((float)sum + bint) * s;
    }
}

static inline long lminl(long a, long b) { return a < b ? a : b; }

extern "C" void kernel_launch(void* const* d_in, const int* in_sizes, int n_in,
                              void* d_out, int out_size, void* d_ws, size_t ws_size,
                              hipStream_t stream) {
    const float* x  = (const float*)d_in[0];
    const float* w1 = (const float*)d_in[1];
    const float* b1 = (const float*)d_in[2];
    const float* w2 = (const float*)d_in[3];
    const float* b2 = (const float*)d_in[4];
    const float* w3 = (const float*)d_in[5];
    const float* b3 = (const float*)d_in[6];
    float* out = (float*)d_out;

    constexpr int B = 512, DIN = 9216, DH = 4096, DOUT = 1000;
    constexpr int SPLITK = 4;

    // workspace carve-up
    char* ws = (char*)d_ws;
    float*       stats = (float*)ws;                       // 256 B
    signed char* xq    = (signed char*)(ws + 256);         // 512*9216
    signed char* w1q   = xq  + (size_t)B * DIN;            // 4096*9216
    signed char* w2q   = w1q + (size_t)DH * DIN;           // 4096*4096
    signed char* w3q   = w2q + (size_t)DH * DH;            // 1024*4096 (padded rows)
    signed char* h1q   = w3q + (size_t)1024 * DH;          // 512*4096
    signed char* h2q   = h1q + (size_t)B * DH;             // 512*4096
    float*       hbuf  = (float*)(h2q + (size_t)B * DH);   // 512*4096 fp32
    int*         acc4  = (int*)(hbuf + (size_t)B * DH);    // SPLITK * 512*4096 int32
    const size_t need  = 256 + (size_t)B*DIN + (size_t)DH*DIN + (size_t)DH*DH + (size_t)1024*DH
                       + 2*(size_t)B*DH + (size_t)B*DH*4 + (size_t)SPLITK*B*DH*4;
    if (ws_size < need) return;  // avoid corrupting memory if workspace too small

    init_stats<<<1, 64, 0, stream>>>(stats);

    auto launch_maxabs = [&](const float* p, long n, int slot) {
        long nchunk = n / 4096;                 // all sizes are multiples of 4096 floats
        int blocks = (int)lminl(nchunk, 2048);
        maxabs_kernel<<<blocks, 256, 0, stream>>>(p, nchunk, stats + slot);
    };
    auto launch_quant = [&](const float* p, signed char* q, long n, int slot, float lo) {
        long nchunk = n / 4096;
        int blocks = (int)lminl(nchunk, 2048);
        quant_kernel<<<blocks, 256, 0, stream>>>(p, q, stats, slot, lo, 127.0f, nchunk);
    };

    // quantize inputs (maxabs then quant back-to-back for L3 reuse)
    launch_maxabs(x, (long)B * DIN, 0);
    launch_quant(x, xq, (long)B * DIN, 0, -128.0f);      // activations: lo = -N_LEVELS-1
    launch_maxabs(w1, (long)DH * DIN, 1);
    launch_quant(w1, w1q, (long)DH * DIN, 1, -127.0f);   // weights: lo = -N_LEVELS
    launch_maxabs(w2, (long)DH * DH, 2);
    launch_quant(w2, w2q, (long)DH * DH, 2, -127.0f);
    launch_maxabs(w3, (long)DOUT * DH, 3);
    launch_quant(w3, w3q, (long)DOUT * DH, 3, -127.0f);

    const long n4_h = (long)B * DH / 4;       // 524288
    const long astr = (long)B * DH;           // acc slice stride (ints)

    // fc1: split-K GEMM (K=9216, 4 slices of 2304) -> private slices, then sum+bias+relu+max
    gemm_q8<64, 128, 2, 4><<<dim3(DH / 128, B / 64, SPLITK), 256, 0, stream>>>(
        xq, w1q, acc4, DIN, DIN / SPLITK, DH, astr);
    finish_relu_kernel<<<2048, 256, 0, stream>>>(acc4, astr, b1, stats, 0, 1, 4, hbuf, n4_h, DH - 1);
    launch_quant(hbuf, h1q, (long)B * DH, 4, -128.0f);

    // fc2: K=4096 in 4 slices of 1024
    gemm_q8<64, 128, 2, 4><<<dim3(DH / 128, B / 64, SPLITK), 256, 0, stream>>>(
        h1q, w2q, acc4, DH, DH / SPLITK, DH, astr);
    finish_relu_kernel<<<2048, 256, 0, stream>>>(acc4, astr, b2, stats, 4, 2, 5, hbuf, n4_h, DH - 1);
    launch_quant(hbuf, h2q, (long)B * DH, 5, -128.0f);

    // fc3: 512x1024 acc per slice (cols >= 1000 garbage, never read), sum+bias (no relu)
    const long astr3 = (long)B * 1024;
    gemm_q8<64, 64, 2, 2><<<dim3(16, B / 64, SPLITK), 256, 0, stream>>>(
        h2q, w3q, acc4, DH, DH / SPLITK, 1024, astr3);
    finish3_kernel<<<B, 256, 0, stream>>>(acc4, astr3, b3, stats, 5, 3, out, DOUT);
}

// Round 7
// 488.036 us; speedup vs baseline: 1.1254x; 1.0732x over previous
//
#include <hip/hip_runtime.h>
#include <hip/hip_bf16.h>

typedef __attribute__((ext_vector_type(4))) int   int32x4;
typedef __attribute__((ext_vector_type(4))) float float4v;

// ---------------- stats layout (floats at ws+0) ----------------
// [0]=absmax_x [1]=absmax_w1 [2]=absmax_w2 [3]=absmax_w3 [4]=hmax1 [5]=hmax2

__global__ void init_stats(float* stats) {
    if (threadIdx.x < 64) stats[threadIdx.x] = 0.0f;
}

// ---------------- fused max|x| over 4 tensors ----------------
// Global chunk space: [0,c1)=x, [c1,c2)=w1, [c2,c3)=w2, [c3,c4)=w3; chunk = 4096 floats.
// Each block owns a contiguous range of cpb chunks (1-2 tensors per block).
// Per-slot maxes in named registers (uniform branches, no dynamic indexing).
__global__ __launch_bounds__(256)
void maxabs4_kernel(const float* __restrict__ p0, const float* __restrict__ p1,
                    const float* __restrict__ p2, const float* __restrict__ p3,
                    long c1, long c2, long c3, long c4, int cpb,
                    float* __restrict__ stats) {
    const int tid = threadIdx.x, lane = tid & 63, wid = tid >> 6;
    __shared__ float red[4][4];
    float ms0 = 0.0f, ms1 = 0.0f, ms2 = 0.0f, ms3 = 0.0f;
    long c = (long)blockIdx.x * cpb;
    long ce = c + cpb; if (ce > c4) ce = c4;
    for (; c < ce; ++c) {
        const float* src; long lc; int slot;
        if (c < c1)      { src = p0; lc = c;      slot = 0; }
        else if (c < c2) { src = p1; lc = c - c1; slot = 1; }
        else if (c < c3) { src = p2; lc = c - c2; slot = 2; }
        else             { src = p3; lc = c - c3; slot = 3; }
        const float4v* p = (const float4v*)src + lc * 1024 + tid;
        float4v v0 = p[0], v1 = p[256], v2 = p[512], v3 = p[768];
        float a = fmaxf(fmaxf(fmaxf(fabsf(v0.x), fabsf(v0.y)), fmaxf(fabsf(v0.z), fabsf(v0.w))),
                        fmaxf(fmaxf(fabsf(v1.x), fabsf(v1.y)), fmaxf(fabsf(v1.z), fabsf(v1.w))));
        float b = fmaxf(fmaxf(fmaxf(fabsf(v2.x), fabsf(v2.y)), fmaxf(fabsf(v2.z), fabsf(v2.w))),
                        fmaxf(fmaxf(fabsf(v3.x), fabsf(v3.y)), fmaxf(fabsf(v3.z), fabsf(v3.w))));
        float m = fmaxf(a, b);
        if      (slot == 0) ms0 = fmaxf(ms0, m);
        else if (slot == 1) ms1 = fmaxf(ms1, m);
        else if (slot == 2) ms2 = fmaxf(ms2, m);
        else                ms3 = fmaxf(ms3, m);
    }
    #pragma unroll
    for (int off = 32; off; off >>= 1) {
        ms0 = fmaxf(ms0, __shfl_xor(ms0, off, 64));
        ms1 = fmaxf(ms1, __shfl_xor(ms1, off, 64));
        ms2 = fmaxf(ms2, __shfl_xor(ms2, off, 64));
        ms3 = fmaxf(ms3, __shfl_xor(ms3, off, 64));
    }
    if (lane == 0) { red[wid][0] = ms0; red[wid][1] = ms1; red[wid][2] = ms2; red[wid][3] = ms3; }
    __syncthreads();
    if (tid < 4) {  // thread s owns slot s -> at most 4 atomics/block, 4 distinct addresses
        float r = fmaxf(fmaxf(red[0][tid], red[1][tid]), fmaxf(red[2][tid], red[3][tid]));
        if (r > 0.0f) atomicMax((unsigned int*)&stats[tid], __float_as_uint(r));
    }
}

// ---------------- fused fp32 -> int8 quantize over 4 tensors ----------------
// clip(rint(x/scale), lo, hi); lo = -128 for activations (slot 0), -127 for weights.
__global__ __launch_bounds__(256)
void quant4_kernel(const float* __restrict__ p0, const float* __restrict__ p1,
                   const float* __restrict__ p2, const float* __restrict__ p3,
                   signed char* __restrict__ q0, signed char* __restrict__ q1,
                   signed char* __restrict__ q2, signed char* __restrict__ q3,
                   long c1, long c2, long c3, long c4, int cpb,
                   const float* __restrict__ stats) {
    const int tid = threadIdx.x;
    const float s0v = stats[0] / 127.0f, s1v = stats[1] / 127.0f;
    const float s2v = stats[2] / 127.0f, s3v = stats[3] / 127.0f;
    long c = (long)blockIdx.x * cpb;
    long ce = c + cpb; if (ce > c4) ce = c4;
    for (; c < ce; ++c) {
        const float* src; signed char* dst; long lc; float sc, lo;
        if (c < c1)      { src = p0; dst = q0; lc = c;      sc = s0v; lo = -128.0f; }
        else if (c < c2) { src = p1; dst = q1; lc = c - c1; sc = s1v; lo = -127.0f; }
        else if (c < c3) { src = p2; dst = q2; lc = c - c2; sc = s2v; lo = -127.0f; }
        else             { src = p3; dst = q3; lc = c - c3; sc = s3v; lo = -127.0f; }
        const float4v* p = (const float4v*)src + lc * 1024 + tid;
        int* d = (int*)dst + lc * 1024 + tid;
        float4v v0 = p[0], v1 = p[256], v2 = p[512], v3 = p[768];
        float4v vs[4] = {v0, v1, v2, v3};
        int packed[4];
        #pragma unroll
        for (int j = 0; j < 4; ++j) {
            float4v v = vs[j];
            int b0 = (int)fminf(fmaxf(rintf(v.x / sc), lo), 127.0f);
            int b1 = (int)fminf(fmaxf(rintf(v.y / sc), lo), 127.0f);
            int b2 = (int)fminf(fmaxf(rintf(v.z / sc), lo), 127.0f);
            int b3 = (int)fminf(fmaxf(rintf(v.w / sc), lo), 127.0f);
            packed[j] = (b0 & 0xff) | ((b1 & 0xff) << 8) | ((b2 & 0xff) << 16) | ((b3 & 0xff) << 24);
        }
        d[0]   = packed[0];
        d[256] = packed[1];
        d[512] = packed[2];
        d[768] = packed[3];
    }
}

// ---------------- single-tensor quantize (h1/h2, scale from stats[slot]) ----------------
__global__ __launch_bounds__(256)
void quant_kernel(const float* __restrict__ src, signed char* __restrict__ dst,
                  const float* __restrict__ stats, int slot,
                  float lo, float hi, long nchunk) {
    const float scale = stats[slot] / 127.0f;
    const int tid = threadIdx.x;
    for (long c = blockIdx.x; c < nchunk; c += gridDim.x) {
        const float4v* p = (const float4v*)src + c * 1024 + tid;
        int* d = (int*)dst + c * 1024 + tid;
        float4v v0 = p[0], v1 = p[256], v2 = p[512], v3 = p[768];
        float4v vs[4] = {v0, v1, v2, v3};
        int packed[4];
        #pragma unroll
        for (int j = 0; j < 4; ++j) {
            float4v v = vs[j];
            int b0 = (int)fminf(fmaxf(rintf(v.x / scale), lo), hi);
            int b1 = (int)fminf(fmaxf(rintf(v.y / scale), lo), hi);
            int b2 = (int)fminf(fmaxf(rintf(v.z / scale), lo), hi);
            int b3 = (int)fminf(fmaxf(rintf(v.w / scale), lo), hi);
            packed[j] = (b0 & 0xff) | ((b1 & 0xff) << 8) | ((b2 & 0xff) << 16) | ((b3 & 0xff) << 24);
        }
        d[0]   = packed[0];
        d[256] = packed[1];
        d[512] = packed[2];
        d[768] = packed[3];
    }
}

// ---------------- split-K int8 GEMM: Acc[z][M,ldacc] = A[M,Kslice_z] @ Bw[N,Kslice_z]^T ----------------
// Each z-slice writes its PRIVATE acc buffer with plain stores (no atomics, no pre-zero).
// 3-stage LDS pipeline, counted vmcnt, XOR-swizzled LDS (pre-swizzled global source).
template <int BM, int BN, int FR, int FC>
__global__ __launch_bounds__(256, 4)
void gemm_q8(const signed char* __restrict__ A, const signed char* __restrict__ Bw,
             int* __restrict__ Acc, int K, int kslice, int ldacc, long accstride) {
    constexpr int BK = 64;
    constexpr int NWC = BN / (FC * 16);
    constexpr int L = BM / 64 + BN / 64;         // gload_lds per thread per stage
    static_assert((BM / (FR * 16)) * (BN / (FC * 16)) == 4, "4 waves");
    constexpr int LDS_A = BM * BK;
    constexpr int LDS_TILE = (BM + BN) * BK;
    __shared__ __align__(16) signed char lds[3][LDS_TILE];

    const int tid  = threadIdx.x;
    const int wid  = tid >> 6;
    const int lane = tid & 63;
    const int wr   = wid / NWC;
    const int wc   = wid % NWC;

    const int brow  = blockIdx.y * BM;
    const int bcol  = blockIdx.x * BN;
    const int kbase = blockIdx.z * kslice;
    int* __restrict__ Accz = Acc + (long)blockIdx.z * accstride;

    const signed char* Ab = A  + (long)brow * K + kbase;
    const signed char* Bb = Bw + (long)bcol * K + kbase;

    const int srow = tid >> 2;                        // row within tile handled when staging
    const int scb  = (tid & 3) * 16;                  // LDS byte column (16B chunk), linear dest
    const int scsrc = scb ^ (((srow >> 1) & 3) << 4); // inverse-swizzled global column

    int32x4 zero = {0, 0, 0, 0};
    int32x4 acc[FR][FC];
    #pragma unroll
    for (int r = 0; r < FR; ++r)
        #pragma unroll
        for (int c = 0; c < FC; ++c) acc[r][c] = zero;

    auto stage = [&](int buf, int kt) {
        #pragma unroll
        for (int i = 0; i < BM / 64; ++i) {
            __builtin_amdgcn_global_load_lds(
                (const __attribute__((address_space(1))) void*)(Ab + (long)(srow + i * 64) * K + kt + scsrc),
                (__attribute__((address_space(3))) void*)(&lds[buf][(srow + i * 64) * BK + scb]),
                16, 0, 0);
        }
        #pragma unroll
        for (int i = 0; i < BN / 64; ++i) {
            __builtin_amdgcn_global_load_lds(
                (const __attribute__((address_space(1))) void*)(Bb + (long)(srow + i * 64) * K + kt + scsrc),
                (__attribute__((address_space(3))) void*)(&lds[buf][LDS_A + (srow + i * 64) * BK + scb]),
                16, 0, 0);
        }
    };

    const int nt = kslice / BK;
    stage(0, 0);
    if (nt > 1) stage(1, BK);

    for (int t = 0; t < nt; ++t) {
        if (t + 1 < nt) {
            asm volatile("s_waitcnt vmcnt(%0)\n\ts_barrier" :: "n"(L) : "memory");
        } else {
            asm volatile("s_waitcnt vmcnt(0)\n\ts_barrier" ::: "memory");
        }
        if (t + 2 < nt) stage((t + 2) % 3, (t + 2) * BK);

        const signed char* la = &lds[t % 3][0];
        const signed char* lb = &lds[t % 3][LDS_A];
        int32x4 af[FR], bf[FC];
        #pragma unroll
        for (int r = 0; r < FR; ++r) {
            const int row = wr * (FR * 16) + r * 16 + (lane & 15);
            const int col = ((lane >> 4) * 16) ^ (((row >> 1) & 3) << 4);
            af[r] = *(const int32x4*)(la + row * BK + col);
        }
        #pragma unroll
        for (int c = 0; c < FC; ++c) {
            const int row = wc * (FC * 16) + c * 16 + (lane & 15);
            const int col = ((lane >> 4) * 16) ^ (((row >> 1) & 3) << 4);
            bf[c] = *(const int32x4*)(lb + row * BK + col);
        }

        #pragma unroll
        for (int r = 0; r < FR; ++r)
            #pragma unroll
            for (int c = 0; c < FC; ++c)
                acc[r][c] = __builtin_amdgcn_mfma_i32_16x16x64_i8(af[r], bf[c], acc[r][c], 0, 0, 0);
    }

    // epilogue: plain stores into this slice's private acc (every element written once)
    #pragma unroll
    for (int c = 0; c < FC; ++c) {
        const int col = bcol + wc * (FC * 16) + c * 16 + (lane & 15);
        #pragma unroll
        for (int r = 0; r < FR; ++r) {
            const int row0 = brow + wr * (FR * 16) + r * 16 + (lane >> 4) * 4;
            #pragma unroll
            for (int j = 0; j < 4; ++j)
                Accz[(long)(row0 + j) * ldacc + col] = acc[r][c][j];
        }
    }
}

// ---------------- finish (fc1/fc2): sum 4 int32 slices -> fp32, bias+relu+max ----------------
__global__ __launch_bounds__(256)
void finish_relu_kernel(const int* __restrict__ acc, long accstride,
                        const float* __restrict__ bias,
                        float* __restrict__ stats, int a_slot, int w_slot, int h_slot,
                        float* __restrict__ outbuf, long n4, int colmask) {
    const float s = (stats[a_slot] / 127.0f) * (stats[w_slot] / 127.0f);
    const int tid = threadIdx.x;
    const int lane = tid & 63;
    const int wid = tid >> 6;
    __shared__ float red[4];
    float lmax = 0.0f;
    long i = (long)blockIdx.x * blockDim.x + tid;
    long stride = (long)gridDim.x * blockDim.x;
    for (; i < n4; i += stride) {
        int32x4 a0 = ((const int32x4*)acc)[i];
        int32x4 a1 = ((const int32x4*)(acc + accstride))[i];
        int32x4 a2 = ((const int32x4*)(acc + 2 * accstride))[i];
        int32x4 a3 = ((const int32x4*)(acc + 3 * accstride))[i];
        float4v v;
        #pragma unroll
        for (int j = 0; j < 4; ++j) {
            int sum = a0[j] + a1[j] + a2[j] + a3[j];
            int col = (int)((i * 4 + j) & colmask);
            float bint = rintf(bias[col] / s);
            float val = ((float)sum + bint) * s;
            val = fmaxf(val, 0.0f);
            v[j] = val;
            lmax = fmaxf(lmax, val);
        }
        ((float4v*)outbuf)[i] = v;
    }
    #pragma unroll
    for (int off = 32; off; off >>= 1) lmax = fmaxf(lmax, __shfl_xor(lmax, off, 64));
    if (lane == 0) red[wid] = lmax;
    __syncthreads();
    if (tid == 0) {
        float r = fmaxf(fmaxf(red[0], red[1]), fmaxf(red[2], red[3]));
        atomicMax((unsigned int*)&stats[h_slot], __float_as_uint(r));
    }
}

// ---------------- finish (fc3): sum 4 slices of acc[512][1024] -> out[512][1000], bias ----------------
__global__ __launch_bounds__(256)
void finish3_kernel(const int* __restrict__ acc, long accstride,
                    const float* __restrict__ bias,
                    const float* __restrict__ stats, int a_slot, int w_slot,
                    float* __restrict__ out, int ncols) {
    const float s = (stats[a_slot] / 127.0f) * (stats[w_slot] / 127.0f);
    const int row = blockIdx.x;
    for (int col = threadIdx.x; col < ncols; col += blockDim.x) {
        long idx = (long)row * 1024 + col;
        int sum = acc[idx] + acc[idx + accstride] + acc[idx + 2 * accstride] + acc[idx + 3 * accstride];
        float bint = rintf(bias[col] / s);
        out[(long)row * ncols + col] = ((float)sum + bint) * s;
    }
}

static inline long lminl(long a, long b) { return a < b ? a : b; }

extern "C" void kernel_launch(void* const* d_in, const int* in_sizes, int n_in,
                              void* d_out, int out_size, void* d_ws, size_t ws_size,
                              hipStream_t stream) {
    const float* x  = (const float*)d_in[0];
    const float* w1 = (const float*)d_in[1];
    const float* b1 = (const float*)d_in[2];
    const float* w2 = (const float*)d_in[3];
    const float* b2 = (const float*)d_in[4];
    const float* w3 = (const float*)d_in[5];
    const float* b3 = (const float*)d_in[6];
    float* out = (float*)d_out;

    constexpr int B = 512, DIN = 9216, DH = 4096, DOUT = 1000;
    constexpr int SPLITK = 4;

    // workspace carve-up
    char* ws = (char*)d_ws;
    float*       stats = (float*)ws;                       // 256 B
    signed char* xq    = (signed char*)(ws + 256);         // 512*9216
    signed char* w1q   = xq  + (size_t)B * DIN;            // 4096*9216
    signed char* w2q   = w1q + (size_t)DH * DIN;           // 4096*4096
    signed char* w3q   = w2q + (size_t)DH * DH;            // 1024*4096 (padded rows)
    signed char* h1q   = w3q + (size_t)1024 * DH;          // 512*4096
    signed char* h2q   = h1q + (size_t)B * DH;             // 512*4096
    float*       hbuf  = (float*)(h2q + (size_t)B * DH);   // 512*4096 fp32
    int*         acc4  = (int*)(hbuf + (size_t)B * DH);    // SPLITK * 512*4096 int32
    const size_t need  = 256 + (size_t)B*DIN + (size_t)DH*DIN + (size_t)DH*DH + (size_t)1024*DH
                       + 2*(size_t)B*DH + (size_t)B*DH*4 + (size_t)SPLITK*B*DH*4;
    if (ws_size < need) return;  // avoid corrupting memory if workspace too small

    init_stats<<<1, 64, 0, stream>>>(stats);

    // fused prep: chunk boundaries (4096-float chunks)
    const long c1 = (long)B * DIN / 4096;              // 1152  (x)
    const long c2 = c1 + (long)DH * DIN / 4096;        // +9216 (w1)
    const long c3 = c2 + (long)DH * DH / 4096;         // +4096 (w2)
    const long c4 = c3 + (long)DOUT * DH / 4096;       // +1000 (w3)  = 15464
    const int  cpb = 8;
    const int  prep_blocks = (int)((c4 + cpb - 1) / cpb);   // 1933

    maxabs4_kernel<<<prep_blocks, 256, 0, stream>>>(x, w1, w2, w3, c1, c2, c3, c4, cpb, stats);
    quant4_kernel<<<prep_blocks, 256, 0, stream>>>(x, w1, w2, w3, xq, w1q, w2q, w3q,
                                                   c1, c2, c3, c4, cpb, stats);

    const long n4_h = (long)B * DH / 4;       // 524288
    const long astr = (long)B * DH;           // acc slice stride (ints)
    const long nchunk_h = (long)B * DH / 4096;  // 512

    // fc1: split-K GEMM (K=9216, 4 slices of 2304) -> private slices, then sum+bias+relu+max
    gemm_q8<64, 128, 2, 4><<<dim3(DH / 128, B / 64, SPLITK), 256, 0, stream>>>(
        xq, w1q, acc4, DIN, DIN / SPLITK, DH, astr);
    finish_relu_kernel<<<2048, 256, 0, stream>>>(acc4, astr, b1, stats, 0, 1, 4, hbuf, n4_h, DH - 1);
    quant_kernel<<<512, 256, 0, stream>>>(hbuf, h1q, stats, 4, -128.0f, 127.0f, nchunk_h);

    // fc2: K=4096 in 4 slices of 1024
    gemm_q8<64, 128, 2, 4><<<dim3(DH / 128, B / 64, SPLITK), 256, 0, stream>>>(
        h1q, w2q, acc4, DH, DH / SPLITK, DH, astr);
    finish_relu_kernel<<<2048, 256, 0, stream>>>(acc4, astr, b2, stats, 4, 2, 5, hbuf, n4_h, DH - 1);
    quant_kernel<<<512, 256, 0, stream>>>(hbuf, h2q, stats, 5, -128.0f, 127.0f, nchunk_h);

    // fc3: 512x1024 acc per slice (cols >= 1000 garbage, never read), sum+bias (no relu)
    const long astr3 = (long)B * 1024;
    gemm_q8<64, 64, 2, 2><<<dim3(16, B / 64, SPLITK), 256, 0, stream>>>(
        h2q, w3q, acc4, DH, DH / SPLITK, 1024, astr3);
    finish3_kernel<<<B, 256, 0, stream>>>(acc4, astr3, b3, stats, 5, 3, out, DOUT);
}